// Round 6
// baseline (312.068 us; speedup 1.0000x reference)
//
#include <hip/hip_runtime.h>
#include <hip/hip_bf16.h>
#include <math.h>

#define Dm 1024
#define Tm 2048
#define Bm 2
#define Hm 16
#define HDm 64
#define Rm (Bm*Tm)   // 4096 rows
#define QKS 2048     // q|k row stride (dense, V split out)

typedef __attribute__((ext_vector_type(8))) short sh8;    // 8 bf16 (4 VGPRs)
typedef __attribute__((ext_vector_type(4))) float f32x4;  // MFMA C/D frag

#define AS1(p) ((const __attribute__((address_space(1))) void*)(p))
#define AS3(p) ((__attribute__((address_space(3))) void*)(p))

// fp32 -> bf16 bits, round-to-nearest-even
__device__ __forceinline__ short f2bs(float f) {
    union { float f; unsigned u; } v; v.f = f;
    unsigned r = v.u + 0x7FFFu + ((v.u >> 16) & 1u);
    return (short)(r >> 16);
}

// ---------------- weight convert: wq,wk,wv -> wqkv (bf16), wo -> wob ----
// wq is pre-scaled by 0.125 (1/sqrt(64)) so attention skips the scale.
// Exact: power-of-2 scaling commutes with bf16 rounding and fp32 accum.
__global__ __launch_bounds__(256) void convert_w(const float* __restrict__ wq,
                                                 const float* __restrict__ wk,
                                                 const float* __restrict__ wv,
                                                 const float* __restrict__ wo,
                                                 short* __restrict__ wqkv,
                                                 short* __restrict__ wob) {
    int idx = (blockIdx.x * 256 + threadIdx.x) * 4;   // 4 elems/thread, 4M total
    const int M1 = 1 << 20;
    const float* src; short* dst; int off; float sc = 1.0f;
    if (idx < M1)           { src = wq; dst = wqkv;          off = idx; sc = 0.125f; }
    else if (idx < 2*M1)    { src = wk; dst = wqkv + M1;     off = idx - M1; }
    else if (idx < 3*M1)    { src = wv; dst = wqkv + 2*M1;   off = idx - 2*M1; }
    else                    { src = wo; dst = wob;           off = idx - 3*M1; }
    float4 v = *(const float4*)(src + off);
    short4 o;
    o.x = f2bs(v.x*sc); o.y = f2bs(v.y*sc); o.z = f2bs(v.z*sc); o.w = f2bs(v.w*sc);
    *(short4*)(dst + off) = o;
}

// ---------------- LayerNorm: one block (256 thr) per row, bf16 out ------
__global__ __launch_bounds__(256) void ln_kernel(const float* __restrict__ x,
                                                 const float* __restrict__ scale,
                                                 short* __restrict__ out) {
    int row = blockIdx.x;
    int t = threadIdx.x;
    const float4* xr = (const float4*)(x + (size_t)row * Dm);
    float4 v = xr[t];
    float s  = v.x + v.y + v.z + v.w;
    float ss = v.x*v.x + v.y*v.y + v.z*v.z + v.w*v.w;
    #pragma unroll
    for (int off = 32; off; off >>= 1) {
        s  += __shfl_xor(s, off);
        ss += __shfl_xor(ss, off);
    }
    __shared__ float red[8];
    int wave = t >> 6, lane = t & 63;
    if (lane == 0) { red[wave*2] = s; red[wave*2+1] = ss; }
    __syncthreads();
    s  = red[0] + red[2] + red[4] + red[6];
    ss = red[1] + red[3] + red[5] + red[7];
    float mean = s * (1.0f / Dm);
    float var  = ss * (1.0f / Dm) - mean * mean;
    float rstd = 1.0f / sqrtf(var + 1e-5f);
    float4 sc = ((const float4*)scale)[t];
    short4 o;
    o.x = f2bs(sc.x * ((v.x - mean) * rstd) + sc.x);
    o.y = f2bs(sc.y * ((v.y - mean) * rstd) + sc.y);
    o.z = f2bs(sc.z * ((v.z - mean) * rstd) + sc.z);
    o.w = f2bs(sc.w * ((v.w - mean) * rstd) + sc.w);
    ((short4*)(out + (size_t)row * Dm))[t] = o;
}

// ---------------- MFMA GEMM (m97 structure): C = A @ B^T ----------------
// MODE 0: float out + bias + residual (proj GEMM)
// MODE 1: QKV gemm: n<2048 -> bf16 into qk buffer (stride 2048);
//         n>=2048 -> V part stored TRANSPOSED per head: vtg[b][h][d][key]
template<int BN, int MODE>
__global__ __launch_bounds__(256) void gemm_mfma(const short* __restrict__ A,
                                                 const short* __restrict__ B,
                                                 const float* __restrict__ bias,
                                                 const float* __restrict__ res,
                                                 void* __restrict__ Cv,
                                                 short* __restrict__ Vt,
                                                 int M, int N, int K) {
    __shared__ short As[128*32];
    __shared__ short Bs[BN*32];
    __shared__ short Tb[(MODE==1) ? 4*16*68 : 4];   // per-wave transpose bounce
    const int NJ = BN / 32;            // 16x16 j-tiles per wave
    int t = threadIdx.x;
    int lane = t & 63, w = t >> 6;
    int l = lane & 15, quad = lane >> 4;
    int wm = (w & 1) * 64, wn = (w >> 1) * (BN/2);
    int m0 = blockIdx.y * 128, n0 = blockIdx.x * BN;

    f32x4 acc[4][NJ];
    #pragma unroll
    for (int i = 0; i < 4; i++)
        #pragma unroll
        for (int j = 0; j < NJ; j++)
            acc[i][j] = (f32x4){0.f,0.f,0.f,0.f};

    for (int k0 = 0; k0 < K; k0 += 32) {
        __syncthreads();
        #pragma unroll
        for (int p = 0; p < 2; p++) {            // A tile: 128 rows
            int off = p*4096 + t*16;             // LDS byte offset
            int row = off >> 6;
            int c = ((off >> 4) & 3) ^ (row & 3);
            const short* ga = A + (size_t)(m0 + row) * K + k0 + c*8;
            __builtin_amdgcn_global_load_lds(AS1(ga), AS3((char*)As + off), 16, 0, 0);
        }
        #pragma unroll
        for (int p = 0; p < BN/64; p++) {        // B tile: BN rows
            int off = p*4096 + t*16;
            int row = off >> 6;
            int c = ((off >> 4) & 3) ^ (row & 3);
            const short* gb = B + (size_t)(n0 + row) * K + k0 + c*8;
            __builtin_amdgcn_global_load_lds(AS1(gb), AS3((char*)Bs + off), 16, 0, 0);
        }
        __syncthreads();
        sh8 af[4], bf[NJ];
        #pragma unroll
        for (int i = 0; i < 4; i++) {
            int m = wm + i*16 + l;
            af[i] = *(const sh8*)((const char*)As + m*64 + ((quad ^ (m & 3)) * 16));
        }
        #pragma unroll
        for (int j = 0; j < NJ; j++) {
            int n = wn + j*16 + l;
            bf[j] = *(const sh8*)((const char*)Bs + n*64 + ((quad ^ (n & 3)) * 16));
        }
        #pragma unroll
        for (int i = 0; i < 4; i++)
            #pragma unroll
            for (int j = 0; j < NJ; j++)
                acc[i][j] = __builtin_amdgcn_mfma_f32_16x16x32_bf16(af[i], bf[j], acc[i][j], 0, 0, 0);
    }
    // epilogue
    if (MODE == 0) {
        #pragma unroll
        for (int i = 0; i < 4; i++)
            #pragma unroll
            for (int j = 0; j < NJ; j++)
                #pragma unroll
                for (int r = 0; r < 4; r++) {
                    int m = m0 + wm + i*16 + quad*4 + r;
                    int n = n0 + wn + j*16 + l;
                    float vv = acc[i][j][r] + bias[n] + res[(size_t)m * N + n];
                    ((float*)Cv)[(size_t)m * N + n] = vv;
                }
    } else {
        if (n0 < 2048) {
            // q,k part: bf16 store at dense stride 2048
            #pragma unroll
            for (int i = 0; i < 4; i++)
                #pragma unroll
                for (int j = 0; j < NJ; j++)
                    #pragma unroll
                    for (int r = 0; r < 4; r++) {
                        int m = m0 + wm + i*16 + quad*4 + r;
                        int n = n0 + wn + j*16 + l;
                        ((short*)Cv)[(size_t)m * QKS + n] = f2bs(acc[i][j][r]);
                    }
        } else {
            // V part: transpose via per-wave LDS bounce -> vtg[bh][d][key]
            int bq = m0 >> 11;                    // batch
            int key0 = (m0 & 2047) + wm;          // wave's key base
            int h = (n0 + wn - 2048) >> 6;        // wave covers exactly one head
            short* vout = Vt + ((size_t)(bq*Hm + h) * HDm) * Tm + key0;
            #pragma unroll
            for (int j = 0; j < NJ; j++) {
                #pragma unroll
                for (int i = 0; i < 4; i++) {
                    short4 o;
                    o.x = f2bs(acc[i][j][0]); o.y = f2bs(acc[i][j][1]);
                    o.z = f2bs(acc[i][j][2]); o.w = f2bs(acc[i][j][3]);
                    *(short4*)&Tb[w*(16*68) + l*68 + i*16 + quad*4] = o;
                }
                #pragma unroll
                for (int st = 0; st < 2; st++) {
                    int rr = st*8 + (lane >> 3);
                    int cc = lane & 7;
                    sh8 vv = *(const sh8*)&Tb[w*(16*68) + rr*68 + cc*8];
                    *(sh8*)(vout + (size_t)(j*16 + rr) * Tm + cc*8) = vv;
                }
            }
        }
    }
}

// ---------------- MFMA flash attention, S^T form, no online max ---------
// v6 = v4 structure (no split-K) + v5 refinements. Grid (bh=32, xi=32),
// all 1024 blocks co-resident (LDS exactly 40960 B -> 4 blocks/CU).
// Balanced qt table: co-resident stride-256 blocks share c=xi&7, span
// k=xi>>3 -> qt in {c, 15-c, 16+c, 31-c}: chunk sum 66 per CU.
// XCD = bh%8 -> per-bh K/V resident in one XCD L2 (12 MB FETCH measured).
// Hoisted staging pointers; wq pre-scaled (no mul before exp); setprio
// around MFMA clusters (T5).
__global__ __launch_bounds__(256) void attn_mfma(const short* __restrict__ qk,
                                                 const short* __restrict__ vtg,
                                                 short* __restrict__ ctx) {
    __shared__ short Kl[2][64*64];     // 16 KB: XOR-swizzled, double-buffered
    __shared__ short Vl[2][64*64];     // 16 KB: V^T [d][key], swizzled, dbuf
    __shared__ short Pl[4][16*64];     //  8 KB: granule-swizzled P bounce
    int t = threadIdx.x;
    int lane = t & 63, w = t >> 6;
    int l = lane & 15, quad = lane >> 4;
    int bh = blockIdx.x;               // 0..31 (XCD = bh%8)
    int xi = blockIdx.y;               // 0..31
    int cc0 = xi & 7, kk0 = xi >> 3;
    int qt = (kk0 == 0) ? cc0 : (kk0 == 1) ? (15 - cc0)
           : (kk0 == 2) ? (16 + cc0) : (31 - cc0);
    int b = bh >> 4, h = bh & 15;
    size_t rbase = (size_t)b * Tm;
    const short* qp0 = qk + rbase * QKS + h*HDm;
    const short* kp0 = qp0 + Dm;
    const short* vh  = vtg + ((size_t)bh * HDm) * Tm;
    int qtbase = qt * 64;

    // Q fragments (B-operand): qf[s] = Q[q=l][dim s*32 + quad*8 + j]
    sh8 qf0, qf1;
    {
        const short* qp = qp0 + (size_t)(qtbase + w*16 + l) * QKS + quad*8;
        qf0 = *(const sh8*)qp;
        qf1 = *(const sh8*)(qp + 32);
    }
    f32x4 O[4] = {{0,0,0,0},{0,0,0,0},{0,0,0,0},{0,0,0,0}};
    float ps[4] = {0.f, 0.f, 0.f, 0.f};

    // ---- hoisted staging addresses (advance by constants per chunk) ----
    int offA = t*16, offB = 4096 + t*16;
    int rowA = offA >> 7, rowB = offB >> 7;
    int swA = ((offA >> 4) & 7) ^ (rowA & 7);
    int swB = ((offB >> 4) & 7) ^ (rowB & 7);
    const short* gkA = kp0 + (size_t)rowA * QKS + swA*8;
    const short* gkB = kp0 + (size_t)rowB * QKS + swB*8;
    const short* gvA = vh + (size_t)rowA * Tm + swA*8;
    const short* gvB = vh + (size_t)rowB * Tm + swB*8;

#define STAGE(KD, VD) do { \
    __builtin_amdgcn_global_load_lds(AS1(gkA), AS3((char*)(KD) + offA), 16, 0, 0); \
    __builtin_amdgcn_global_load_lds(AS1(gkB), AS3((char*)(KD) + offB), 16, 0, 0); \
    __builtin_amdgcn_global_load_lds(AS1(gvA), AS3((char*)(VD) + offA), 16, 0, 0); \
    __builtin_amdgcn_global_load_lds(AS1(gvB), AS3((char*)(VD) + offB), 16, 0, 0); \
    gkA += 64*QKS; gkB += 64*QKS; gvA += 64; gvB += 64; } while (0)

    STAGE(Kl[0], Vl[0]);
    __syncthreads();

    int swl = l & 7;                   // Pl granule swizzle key
    int cur = 0;
    for (int kc = 0; kc <= qt; kc++) {
        int kbase = kc * 64;
        if (kc < qt) {
            if (cur) STAGE(Kl[0], Vl[0]); else STAGE(Kl[1], Vl[1]);
        }

        // ---- S^T = K Q^T : S[kt] row=key(quad*4+r), col=q(l) ----
        f32x4 S[4];
        __builtin_amdgcn_s_setprio(1);
        #pragma unroll
        for (int kt = 0; kt < 4; kt++) {
            const f32x4 z = {0.f,0.f,0.f,0.f};
            int key = kt*16 + l;
            const char* kb = (const char*)Kl[cur] + key*128;
            int sw = key & 7;
            sh8 k0 = *(const sh8*)(kb + ((quad ^ sw) * 16));
            sh8 k1 = *(const sh8*)(kb + (((4 + quad) ^ sw) * 16));
            f32x4 s = __builtin_amdgcn_mfma_f32_16x16x32_bf16(k0, qf0, z, 0, 0, 0);
            s = __builtin_amdgcn_mfma_f32_16x16x32_bf16(k1, qf1, s, 0, 0, 0);
            S[kt] = s;
        }
        __builtin_amdgcn_s_setprio(0);
        // ---- p = exp(s) (wq pre-scaled), mask, accumulate l, pack bf16 ----
        bool needmask = (kbase + 63 > qtbase + w*16);
        int qrow = qtbase + w*16 + l;
        #pragma unroll
        for (int kt = 0; kt < 4; kt++) {
            float p[4];
            if (needmask) {
                #pragma unroll
                for (int r = 0; r < 4; r++) {
                    int key = kbase + kt*16 + quad*4 + r;
                    p[r] = (key > qrow) ? 0.f : __expf(S[kt][r]);
                }
            } else {
                #pragma unroll
                for (int r = 0; r < 4; r++)
                    p[r] = __expf(S[kt][r]);
            }
            ps[kt] += (p[0] + p[1]) + (p[2] + p[3]);
            __hip_bfloat162 pa = __float22bfloat162_rn({p[0], p[1]});
            __hip_bfloat162 pb = __float22bfloat162_rn({p[2], p[3]});
            union { __hip_bfloat162 hh[2]; short4 s4; } u;
            u.hh[0] = pa; u.hh[1] = pb;
            int g = (kt*2 + (quad >> 1)) ^ swl;
            *(short4*)&Pl[w][l*64 + g*8 + (quad & 1)*4] = u.s4;
        }
        // ---- P A-frags (granule-swizzled read) ----
        sh8 p0 = *(const sh8*)&Pl[w][l*64 + ((quad ^ swl) * 8)];
        sh8 p1 = *(const sh8*)&Pl[w][l*64 + (((4 + quad) ^ swl) * 8)];
        // ---- O += P V (C: row=q quad*4+r, col=dim l) ----
        __builtin_amdgcn_s_setprio(1);
        #pragma unroll
        for (int dt = 0; dt < 4; dt++) {
            int d = dt*16 + l;
            const char* vb = (const char*)Vl[cur] + d*128;
            int sw = d & 7;
            sh8 v0 = *(const sh8*)(vb + ((quad ^ sw) * 16));
            sh8 v1 = *(const sh8*)(vb + (((4 + quad) ^ sw) * 16));
            O[dt] = __builtin_amdgcn_mfma_f32_16x16x32_bf16(p0, v0, O[dt], 0, 0, 0);
            O[dt] = __builtin_amdgcn_mfma_f32_16x16x32_bf16(p1, v1, O[dt], 0, 0, 0);
        }
        __builtin_amdgcn_s_setprio(0);
        __syncthreads();   // drains prefetch gload_lds (issued pre-compute)
        cur ^= 1;
    }
#undef STAGE

    // ---- epilogue: reduce l across quads, normalize, store ----
    float psum = (ps[0] + ps[1]) + (ps[2] + ps[3]);
    psum += __shfl_xor(psum, 16);
    psum += __shfl_xor(psum, 32);
    #pragma unroll
    for (int r = 0; r < 4; r++) {
        int src = (lane & 48) | (((lane >> 4) << 2) + r);
        float inv = 1.0f / __shfl(psum, src);
        int row = qtbase + w*16 + quad*4 + r;
        #pragma unroll
        for (int dt = 0; dt < 4; dt++)
            ctx[(rbase + row) * Dm + h*HDm + dt*16 + l] = f2bs(O[dt][r] * inv);
    }
}

// ---------------- launch ----------------
extern "C" void kernel_launch(void* const* d_in, const int* in_sizes, int n_in,
                              void* d_out, int out_size, void* d_ws, size_t ws_size,
                              hipStream_t stream) {
    const float* x   = (const float*)d_in[0];
    const float* wq  = (const float*)d_in[1];
    const float* wk  = (const float*)d_in[2];
    const float* wv  = (const float*)d_in[3];
    const float* wo  = (const float*)d_in[4];
    const float* bo  = (const float*)d_in[5];
    const float* ln1 = (const float*)d_in[6];
    const float* ln2 = (const float*)d_in[7];
    float* out = (float*)d_out;

    short* lnb  = (short*)d_ws;                      // 4096*1024 = 4M sh
    short* ctxb = lnb  + (size_t)Rm*Dm;              // 4M sh
    short* qk   = ctxb + (size_t)Rm*Dm;              // 8M sh
    short* vtg  = qk   + (size_t)Rm*QKS;             // 4M sh
    short* wqkv = vtg  + (size_t)Bm*Hm*HDm*Tm;       // 3M sh
    short* wob  = wqkv + (size_t)3*Dm*Dm;            // 1M sh

    dim3 qgrid(3072/128, Rm/128);  // (24, 32)
    dim3 pgrid(Dm/128,   Rm/128);  // (8, 32): proj now 128x128 tile
    dim3 agrid(32, 32);            // (bh, xi) unpaired, balanced qt table

    convert_w<<<4096, 256, 0, stream>>>(wq, wk, wv, wo, wqkv, wob);

    // ---- Block 1 ----
    ln_kernel<<<Rm, 256, 0, stream>>>(x, ln1, lnb);
    gemm_mfma<128, 1><<<qgrid, 256, 0, stream>>>(lnb, wqkv, nullptr, nullptr, qk, vtg, Rm, 3072, Dm);
    attn_mfma<<<agrid, 256, 0, stream>>>(qk, vtg, ctxb);
    gemm_mfma<128, 0><<<pgrid, 256, 0, stream>>>(ctxb, wob, bo, x, out, nullptr, Rm, Dm, Dm);

    // ---- Block 2 (same weights, ln2) ----
    ln_kernel<<<Rm, 256, 0, stream>>>(out, ln2, lnb);
    gemm_mfma<128, 1><<<qgrid, 256, 0, stream>>>(lnb, wqkv, nullptr, nullptr, qk, vtg, Rm, 3072, Dm);
    attn_mfma<<<agrid, 256, 0, stream>>>(qk, vtg, ctxb);
    gemm_mfma<128, 0><<<pgrid, 256, 0, stream>>>(ctxb, wob, bo, out, out, nullptr, Rm, Dm, Dm);
}

// Round 7
// 299.621 us; speedup vs baseline: 1.0415x; 1.0415x over previous
//
#include <hip/hip_runtime.h>
#include <hip/hip_bf16.h>
#include <math.h>

#define Dm 1024
#define Tm 2048
#define Bm 2
#define Hm 16
#define HDm 64
#define Rm (Bm*Tm)   // 4096 rows
#define QKS 2048     // q|k row stride (dense, V split out)

typedef __attribute__((ext_vector_type(8))) short sh8;      // 8 bf16 (4 VGPRs)
typedef __attribute__((ext_vector_type(4))) float f32x4;    // 16x16 C/D frag
typedef __attribute__((ext_vector_type(16))) float f32x16;  // 32x32 C/D frag

#define AS1(p) ((const __attribute__((address_space(1))) void*)(p))
#define AS3(p) ((__attribute__((address_space(3))) void*)(p))

// fp32 -> bf16 bits, round-to-nearest-even
__device__ __forceinline__ short f2bs(float f) {
    union { float f; unsigned u; } v; v.f = f;
    unsigned r = v.u + 0x7FFFu + ((v.u >> 16) & 1u);
    return (short)(r >> 16);
}

// ---------------- weight convert: wq,wk,wv -> wqkv (bf16), wo -> wob ----
// wq pre-scaled by 0.125 (1/sqrt(64)): exact (pow2 commutes with rounding).
__global__ __launch_bounds__(256) void convert_w(const float* __restrict__ wq,
                                                 const float* __restrict__ wk,
                                                 const float* __restrict__ wv,
                                                 const float* __restrict__ wo,
                                                 short* __restrict__ wqkv,
                                                 short* __restrict__ wob) {
    int idx = (blockIdx.x * 256 + threadIdx.x) * 4;   // 4 elems/thread, 4M total
    const int M1 = 1 << 20;
    const float* src; short* dst; int off; float sc = 1.0f;
    if (idx < M1)           { src = wq; dst = wqkv;          off = idx; sc = 0.125f; }
    else if (idx < 2*M1)    { src = wk; dst = wqkv + M1;     off = idx - M1; }
    else if (idx < 3*M1)    { src = wv; dst = wqkv + 2*M1;   off = idx - 2*M1; }
    else                    { src = wo; dst = wob;           off = idx - 3*M1; }
    float4 v = *(const float4*)(src + off);
    short4 o;
    o.x = f2bs(v.x*sc); o.y = f2bs(v.y*sc); o.z = f2bs(v.z*sc); o.w = f2bs(v.w*sc);
    *(short4*)(dst + off) = o;
}

// ---------------- LayerNorm: one block (256 thr) per row, bf16 out ------
__global__ __launch_bounds__(256) void ln_kernel(const float* __restrict__ x,
                                                 const float* __restrict__ scale,
                                                 short* __restrict__ out) {
    int row = blockIdx.x;
    int t = threadIdx.x;
    const float4* xr = (const float4*)(x + (size_t)row * Dm);
    float4 v = xr[t];
    float s  = v.x + v.y + v.z + v.w;
    float ss = v.x*v.x + v.y*v.y + v.z*v.z + v.w*v.w;
    #pragma unroll
    for (int off = 32; off; off >>= 1) {
        s  += __shfl_xor(s, off);
        ss += __shfl_xor(ss, off);
    }
    __shared__ float red[8];
    int wave = t >> 6, lane = t & 63;
    if (lane == 0) { red[wave*2] = s; red[wave*2+1] = ss; }
    __syncthreads();
    s  = red[0] + red[2] + red[4] + red[6];
    ss = red[1] + red[3] + red[5] + red[7];
    float mean = s * (1.0f / Dm);
    float var  = ss * (1.0f / Dm) - mean * mean;
    float rstd = 1.0f / sqrtf(var + 1e-5f);
    float4 sc = ((const float4*)scale)[t];
    short4 o;
    o.x = f2bs(sc.x * ((v.x - mean) * rstd) + sc.x);
    o.y = f2bs(sc.y * ((v.y - mean) * rstd) + sc.y);
    o.z = f2bs(sc.z * ((v.z - mean) * rstd) + sc.z);
    o.w = f2bs(sc.w * ((v.w - mean) * rstd) + sc.w);
    ((short4*)(out + (size_t)row * Dm))[t] = o;
}

// ---------------- MFMA GEMM (m97 structure): C = A @ B^T ----------------
// MODE 0: float out + bias + residual (proj GEMM)
// MODE 1: QKV gemm: n<2048 -> bf16 into qk buffer (stride 2048);
//         n>=2048 -> V stored transposed per head AND key-permuted within
//         each 16-key group (pi: quads 1<->2) so attn's PV A-frag is
//         lane-local: vtg[bh][d][key'].
template<int BN, int MODE>
__global__ __launch_bounds__(256) void gemm_mfma(const short* __restrict__ A,
                                                 const short* __restrict__ B,
                                                 const float* __restrict__ bias,
                                                 const float* __restrict__ res,
                                                 void* __restrict__ Cv,
                                                 short* __restrict__ Vt,
                                                 int M, int N, int K) {
    __shared__ short As[128*32];
    __shared__ short Bs[BN*32];
    __shared__ short Tb[(MODE==1) ? 4*16*68 : 4];   // per-wave transpose bounce
    const int NJ = BN / 32;            // 16x16 j-tiles per wave
    int t = threadIdx.x;
    int lane = t & 63, w = t >> 6;
    int l = lane & 15, quad = lane >> 4;
    int wm = (w & 1) * 64, wn = (w >> 1) * (BN/2);
    int m0 = blockIdx.y * 128, n0 = blockIdx.x * BN;

    f32x4 acc[4][NJ];
    #pragma unroll
    for (int i = 0; i < 4; i++)
        #pragma unroll
        for (int j = 0; j < NJ; j++)
            acc[i][j] = (f32x4){0.f,0.f,0.f,0.f};

    for (int k0 = 0; k0 < K; k0 += 32) {
        __syncthreads();
        #pragma unroll
        for (int p = 0; p < 2; p++) {            // A tile: 128 rows
            int off = p*4096 + t*16;             // LDS byte offset
            int row = off >> 6;
            int c = ((off >> 4) & 3) ^ (row & 3);
            const short* ga = A + (size_t)(m0 + row) * K + k0 + c*8;
            __builtin_amdgcn_global_load_lds(AS1(ga), AS3((char*)As + off), 16, 0, 0);
        }
        #pragma unroll
        for (int p = 0; p < BN/64; p++) {        // B tile: BN rows
            int off = p*4096 + t*16;
            int row = off >> 6;
            int c = ((off >> 4) & 3) ^ (row & 3);
            const short* gb = B + (size_t)(n0 + row) * K + k0 + c*8;
            __builtin_amdgcn_global_load_lds(AS1(gb), AS3((char*)Bs + off), 16, 0, 0);
        }
        __syncthreads();
        sh8 af[4], bf[NJ];
        #pragma unroll
        for (int i = 0; i < 4; i++) {
            int m = wm + i*16 + l;
            af[i] = *(const sh8*)((const char*)As + m*64 + ((quad ^ (m & 3)) * 16));
        }
        #pragma unroll
        for (int j = 0; j < NJ; j++) {
            int n = wn + j*16 + l;
            bf[j] = *(const sh8*)((const char*)Bs + n*64 + ((quad ^ (n & 3)) * 16));
        }
        #pragma unroll
        for (int i = 0; i < 4; i++)
            #pragma unroll
            for (int j = 0; j < NJ; j++)
                acc[i][j] = __builtin_amdgcn_mfma_f32_16x16x32_bf16(af[i], bf[j], acc[i][j], 0, 0, 0);
    }
    // epilogue
    if (MODE == 0) {
        #pragma unroll
        for (int i = 0; i < 4; i++)
            #pragma unroll
            for (int j = 0; j < NJ; j++)
                #pragma unroll
                for (int r = 0; r < 4; r++) {
                    int m = m0 + wm + i*16 + quad*4 + r;
                    int n = n0 + wn + j*16 + l;
                    float vv = acc[i][j][r] + bias[n] + res[(size_t)m * N + n];
                    ((float*)Cv)[(size_t)m * N + n] = vv;
                }
    } else {
        if (n0 < 2048) {
            // q,k part: bf16 store at dense stride 2048
            #pragma unroll
            for (int i = 0; i < 4; i++)
                #pragma unroll
                for (int j = 0; j < NJ; j++)
                    #pragma unroll
                    for (int r = 0; r < 4; r++) {
                        int m = m0 + wm + i*16 + quad*4 + r;
                        int n = n0 + wn + j*16 + l;
                        ((short*)Cv)[(size_t)m * QKS + n] = f2bs(acc[i][j][r]);
                    }
        } else {
            // V part: transpose + pi-permute -> vtg[bh][d][key']
            // pi swaps sub-positions 4-7 <-> 8-11 per 16-key group: quad' =
            // bit-swap(quad) (0->0, 1->2, 2->1, 3->3).
            int bq = m0 >> 11;                    // batch
            int key0 = (m0 & 2047) + wm;          // wave's key base
            int h = (n0 + wn - 2048) >> 6;        // wave covers exactly one head
            int quad2 = ((quad & 1) << 1) | (quad >> 1);
            short* vout = Vt + ((size_t)(bq*Hm + h) * HDm) * Tm + key0;
            #pragma unroll
            for (int j = 0; j < NJ; j++) {
                #pragma unroll
                for (int i = 0; i < 4; i++) {
                    short4 o;
                    o.x = f2bs(acc[i][j][0]); o.y = f2bs(acc[i][j][1]);
                    o.z = f2bs(acc[i][j][2]); o.w = f2bs(acc[i][j][3]);
                    *(short4*)&Tb[w*(16*68) + l*68 + i*16 + quad2*4] = o;
                }
                #pragma unroll
                for (int st = 0; st < 2; st++) {
                    int rr = st*8 + (lane >> 3);
                    int cc = lane & 7;
                    sh8 vv = *(const sh8*)&Tb[w*(16*68) + rr*68 + cc*8];
                    *(sh8*)(vout + (size_t)(j*16 + rr) * Tm + cc*8) = vv;
                }
            }
        }
    }
}

// ---------------- MFMA flash attention, 32x32 S^T form, lane-local P ----
// v7: 128-thread blocks (2 waves x 32 q), QBLK=64, grid (bh=32, xi=32),
// balanced qt table (v4), XCD = bh%8. S^T = K Q^T via 32x32x16 MFMA:
// lane (l31,hi) reg r holds S[key=(r&3)+8*(r>>2)+4*hi][q=l31]. With V
// stored in pi-permuted key order, the lane's own exp'd regs packed in
// order ARE the PV A-fragment (keys hi*8+j map to regs via pi) -> P never
// touches LDS or cross-lane ops. DS per chunk: K 8KB + V 8KB per wave.
__global__ __launch_bounds__(128) void attn_mfma(const short* __restrict__ qk,
                                                 const short* __restrict__ vtg,
                                                 short* __restrict__ ctx) {
    __shared__ short Kl[2][64*64];     // 16 KB: XOR-swizzled, double-buffered
    __shared__ short Vl[2][64*64];     // 16 KB: V^T permuted, swizzled, dbuf
    int t = threadIdx.x;               // 0..127
    int lane = t & 63, w = t >> 6;     // 2 waves
    int l31 = lane & 31, hi = lane >> 5;
    int bh = blockIdx.x;               // 0..31 (XCD = bh%8)
    int xi = blockIdx.y;               // 0..31
    int cc0 = xi & 7, kk0 = xi >> 3;
    int qt = (kk0 == 0) ? cc0 : (kk0 == 1) ? (15 - cc0)
           : (kk0 == 2) ? (16 + cc0) : (31 - cc0);
    int b = bh >> 4, h = bh & 15;
    size_t rbase = (size_t)b * Tm;
    const short* qp0 = qk + rbase * QKS + h*HDm;
    const short* kp0 = qp0 + Dm;
    const short* vh  = vtg + ((size_t)bh * HDm) * Tm;
    int qtbase = qt * 64;
    int qrow = qtbase + w*32 + l31;

    // Q B-frags: qf[s] = Q[q=l31][d = s*16 + hi*8 + j]
    sh8 qf[4];
    {
        const short* qp = qp0 + (size_t)qrow * QKS + hi*8;
        qf[0] = *(const sh8*)qp;
        qf[1] = *(const sh8*)(qp + 16);
        qf[2] = *(const sh8*)(qp + 32);
        qf[3] = *(const sh8*)(qp + 48);
    }

    f32x16 O0, O1;
    #pragma unroll
    for (int i = 0; i < 16; i++) { O0[i] = 0.f; O1[i] = 0.f; }
    float ps = 0.f;

    // ---- hoisted staging (128 thr stage 8KB K + 8KB V per chunk) ----
    int trow = t >> 3;                       // 0..15
    int c8 = ((t & 7) ^ (trow & 7)) * 8;     // swizzled chunk (shorts)
    int ldsoff = t * 16;                     // bytes; +p*2048 per sub-load
    const short* gk0 = kp0 + (size_t)trow * QKS + c8;
    const short* gk1 = gk0 + (size_t)16*QKS;
    const short* gk2 = gk0 + (size_t)32*QKS;
    const short* gk3 = gk0 + (size_t)48*QKS;
    const short* gv0 = vh + (size_t)trow * Tm + c8;
    const short* gv1 = gv0 + (size_t)16*Tm;
    const short* gv2 = gv0 + (size_t)32*Tm;
    const short* gv3 = gv0 + (size_t)48*Tm;

#define STAGE(KD, VD) do { \
    __builtin_amdgcn_global_load_lds(AS1(gk0), AS3((char*)(KD) + ldsoff), 16, 0, 0); \
    __builtin_amdgcn_global_load_lds(AS1(gk1), AS3((char*)(KD) + 2048 + ldsoff), 16, 0, 0); \
    __builtin_amdgcn_global_load_lds(AS1(gk2), AS3((char*)(KD) + 4096 + ldsoff), 16, 0, 0); \
    __builtin_amdgcn_global_load_lds(AS1(gk3), AS3((char*)(KD) + 6144 + ldsoff), 16, 0, 0); \
    __builtin_amdgcn_global_load_lds(AS1(gv0), AS3((char*)(VD) + ldsoff), 16, 0, 0); \
    __builtin_amdgcn_global_load_lds(AS1(gv1), AS3((char*)(VD) + 2048 + ldsoff), 16, 0, 0); \
    __builtin_amdgcn_global_load_lds(AS1(gv2), AS3((char*)(VD) + 4096 + ldsoff), 16, 0, 0); \
    __builtin_amdgcn_global_load_lds(AS1(gv3), AS3((char*)(VD) + 6144 + ldsoff), 16, 0, 0); \
    gk0 += (size_t)64*QKS; gk1 += (size_t)64*QKS; gk2 += (size_t)64*QKS; gk3 += (size_t)64*QKS; \
    gv0 += 64; gv1 += 64; gv2 += 64; gv3 += 64; } while (0)

    STAGE(Kl[0], Vl[0]);
    __syncthreads();

    int cur = 0;
    for (int kc = 0; kc <= qt; kc++) {
        int kbase = kc * 64;
        if (kc < qt) {
            if (cur) STAGE(Kl[0], Vl[0]); else STAGE(Kl[1], Vl[1]);
        }

        const char* Kb = (const char*)Kl[cur];
        bool needmask = (kbase + 63 > qtbase + w*32);
        sh8 pa[4];                       // PV A-frags (lane-local!)
        #pragma unroll
        for (int kt = 0; kt < 2; kt++) {
            // ---- S^T tile: rows keys kt*32.., cols q ----
            int key = kt*32 + l31;
            const char* kr = Kb + key*128;
            int sw = key & 7;
            f32x16 c;
            #pragma unroll
            for (int i = 0; i < 16; i++) c[i] = 0.f;
            #pragma unroll
            for (int s = 0; s < 4; s++) {
                sh8 kf = *(const sh8*)(kr + (((s*2 + hi) ^ sw) * 16));
                c = __builtin_amdgcn_mfma_f32_32x32x16_bf16(kf, qf[s], c, 0, 0, 0);
            }
            // ---- p = exp(s) (wq pre-scaled), causal mask ----
            float p_[16];
            if (needmask) {
                #pragma unroll
                for (int r = 0; r < 16; r++) {
                    int key_r = kbase + kt*32 + (r&3) + 8*(r>>2) + 4*hi;
                    p_[r] = (key_r > qrow) ? 0.f : __expf(c[r]);
                }
            } else {
                #pragma unroll
                for (int r = 0; r < 16; r++) p_[r] = __expf(c[r]);
            }
            ps += (((p_[0]+p_[1])+(p_[2]+p_[3])) + ((p_[4]+p_[5])+(p_[6]+p_[7])))
                + (((p_[8]+p_[9])+(p_[10]+p_[11])) + ((p_[12]+p_[13])+(p_[14]+p_[15])));
            // ---- pack regs in order: pi makes this the A-frag ----
            #pragma unroll
            for (int gg = 0; gg < 2; gg++) {
                union { __hip_bfloat162 h2[4]; sh8 s8; } u;
                u.h2[0] = __float22bfloat162_rn({p_[gg*8+0], p_[gg*8+1]});
                u.h2[1] = __float22bfloat162_rn({p_[gg*8+2], p_[gg*8+3]});
                u.h2[2] = __float22bfloat162_rn({p_[gg*8+4], p_[gg*8+5]});
                u.h2[3] = __float22bfloat162_rn({p_[gg*8+6], p_[gg*8+7]});
                pa[kt*2 + gg] = u.s8;
            }
        }
        // ---- O += P V (V in pi-permuted key order) ----
        const char* Vb = (const char*)Vl[cur];
        {
            int d = l31;
            const char* vr = Vb + d*128;
            int sw = d & 7;
            #pragma unroll
            for (int G = 0; G < 4; G++) {
                sh8 vf = *(const sh8*)(vr + (((G*2 + hi) ^ sw) * 16));
                O0 = __builtin_amdgcn_mfma_f32_32x32x16_bf16(pa[G], vf, O0, 0, 0, 0);
            }
        }
        {
            int d = 32 + l31;
            const char* vr = Vb + d*128;
            int sw = d & 7;
            #pragma unroll
            for (int G = 0; G < 4; G++) {
                sh8 vf = *(const sh8*)(vr + (((G*2 + hi) ^ sw) * 16));
                O1 = __builtin_amdgcn_mfma_f32_32x32x16_bf16(pa[G], vf, O1, 0, 0, 0);
            }
        }
        __syncthreads();   // drains prefetch gload_lds (issued pre-compute)
        cur ^= 1;
    }
#undef STAGE

    // ---- epilogue: lane's ps covers its 32 keys of col q=l31 ----
    ps += __shfl_xor(ps, 32);          // full denominator for q=l31
    float inv_own = 1.0f / ps;
    short* cp = ctx + (rbase + qtbase + w*32) * Dm + h*HDm + l31;
    #pragma unroll
    for (int r = 0; r < 16; r++) {
        int rl = (r&3) + 8*(r>>2) + 4*hi;          // q-row local 0..31
        float inv = __shfl(inv_own, rl);           // from lane rl (col q=rl)
        cp[(size_t)rl * Dm]      = f2bs(O0[r] * inv);
        cp[(size_t)rl * Dm + 32] = f2bs(O1[r] * inv);
    }
}

// ---------------- launch ----------------
extern "C" void kernel_launch(void* const* d_in, const int* in_sizes, int n_in,
                              void* d_out, int out_size, void* d_ws, size_t ws_size,
                              hipStream_t stream) {
    const float* x   = (const float*)d_in[0];
    const float* wq  = (const float*)d_in[1];
    const float* wk  = (const float*)d_in[2];
    const float* wv  = (const float*)d_in[3];
    const float* wo  = (const float*)d_in[4];
    const float* bo  = (const float*)d_in[5];
    const float* ln1 = (const float*)d_in[6];
    const float* ln2 = (const float*)d_in[7];
    float* out = (float*)d_out;

    short* lnb  = (short*)d_ws;                      // 4096*1024 = 4M sh
    short* ctxb = lnb  + (size_t)Rm*Dm;              // 4M sh
    short* qk   = ctxb + (size_t)Rm*Dm;              // 8M sh
    short* vtg  = qk   + (size_t)Rm*QKS;             // 4M sh
    short* wqkv = vtg  + (size_t)Bm*Hm*HDm*Tm;       // 3M sh
    short* wob  = wqkv + (size_t)3*Dm*Dm;            // 1M sh

    dim3 qgrid(3072/128, Rm/128);  // (24, 32)
    dim3 pgrid(Dm/64,    Rm/128);  // (16, 32): proj BN=64 (round-4 proven)
    dim3 agrid(32, 32);            // (bh, xi), balanced qt table, 128-thr

    convert_w<<<4096, 256, 0, stream>>>(wq, wk, wv, wo, wqkv, wob);

    // ---- Block 1 ----
    ln_kernel<<<Rm, 256, 0, stream>>>(x, ln1, lnb);
    gemm_mfma<128, 1><<<qgrid, 256, 0, stream>>>(lnb, wqkv, nullptr, nullptr, qk, vtg, Rm, 3072, Dm);
    attn_mfma<<<agrid, 128, 0, stream>>>(qk, vtg, ctxb);
    gemm_mfma<64, 0><<<pgrid, 256, 0, stream>>>(ctxb, wob, bo, x, out, nullptr, Rm, Dm, Dm);

    // ---- Block 2 (same weights, ln2) ----
    ln_kernel<<<Rm, 256, 0, stream>>>(out, ln2, lnb);
    gemm_mfma<128, 1><<<qgrid, 256, 0, stream>>>(lnb, wqkv, nullptr, nullptr, qk, vtg, Rm, 3072, Dm);
    attn_mfma<<<agrid, 128, 0, stream>>>(qk, vtg, ctxb);
    gemm_mfma<64, 0><<<pgrid, 256, 0, stream>>>(ctxb, wob, bo, out, out, nullptr, Rm, Dm, Dm);
}